// Round 2
// 400.543 us; speedup vs baseline: 1.0719x; 1.0719x over previous
//
#include <hip/hip_runtime.h>
#include <math.h>

#define B 4
#define N 4096
#define D 256
#define PROJ 64
#define TH_HIDDEN 128
#define K_CAP 255
#define ALPHA 0.2f
#define ROWS_PER_BLOCK 8                         // 2 rows per wave, interleaved
#define BLOCKS_PER_BATCH (N / ROWS_PER_BLOCK)    // 512

// native vector type for nontemporal builtins (HIP_vector_type is rejected)
typedef float floatx4 __attribute__((ext_vector_type(4)));

// Measured A/B ledger (MI355X, this harness):
//   cached 1-row 446.2 | nt 1-row 437.5 | nt 2-row 428.4 (BEST) |
//   cached 2-row 442.0 | nt 4-row 433.5 | fused+fences 531.4
// nt (L2-bypass) wins for the 268 MB single-use adj stream; 2-row interleave
// is the MLP sweet spot (1024 blocks too few waves, 4-row too few blocks).
// R1: prep parallelized — 8 blocks (v | theta split), split-K MAC chains,
//     LDS-staged theta_in, unroll-8 load pipelining. Score/finalize unchanged.
// R2: identical resubmit — R1 bench was an infra failure (container died
//     twice before running), no measurement was taken.

// -------------------- kernel 1: seed argmax, v = Wk*(Wq^T x_seed)/8, theta MLP
// Grid = 2*B. Blocks [0,B): argmax + v. Blocks [B,2B): theta MLP.
// The two halves are independent -> run on different CUs concurrently.
__global__ __launch_bounds__(256) void prep_kernel(
    const float* __restrict__ x, const float* __restrict__ cluster_mask,
    const float* __restrict__ seed_ctx, const float* __restrict__ local_stats,
    const float* __restrict__ Wq, const float* __restrict__ Wk,
    const float* __restrict__ th_w1, const float* __restrict__ th_b1,
    const float* __restrict__ th_w2, const float* __restrict__ th_b2,
    float* v_ws, float* theta_out)
{
    const int bb = blockIdx.x;
    const int t = threadIdx.x;

    if (bb >= B) {
        // ---------------- theta MLP block ----------------
        const int b = bb - B;
        __shared__ float s_in[512];       // [seed_ctx(384), local_stats(128)]
        __shared__ float s_part[256];

        for (int i = t; i < 384; i += 256) s_in[i] = seed_ctx[b * 384 + i];
        if (t < 128) s_in[384 + t] = local_stats[b * 128 + t];
        __syncthreads();

        // h[j] = relu(sum_i s_in[i] * th_w1[i*128+j] + b1[j])
        // split-K: 2 threads per neuron (t<128 -> i in [0,256), else [256,512))
        {
            const int j = t & 127;
            const int h = t >> 7;
            const float* w1 = th_w1 + (size_t)(h * 256) * TH_HIDDEN + j;
            const float* xin = s_in + h * 256;
            float acc = 0.f;
            #pragma unroll 8
            for (int i = 0; i < 256; ++i)
                acc += xin[i] * w1[i * TH_HIDDEN];
            s_part[t] = acc;
        }
        __syncthreads();
        if (t < TH_HIDDEN)
            s_part[t] = fmaxf(s_part[t] + s_part[t + 128] + th_b1[t], 0.f);
        __syncthreads();
        // theta = h @ th_w2 + b2  (128 terms, wave reduce)
        if (t < 64) {
            float a2 = s_part[t] * th_w2[t] + s_part[t + 64] * th_w2[t + 64];
            for (int off = 32; off > 0; off >>= 1)
                a2 += __shfl_down(a2, off, 64);
            if (t == 0) theta_out[b] = a2 + th_b2[0];
        }
        return;
    }

    // ---------------- argmax + v block ----------------
    const int b = bb;
    __shared__ float s_red[256];
    __shared__ int   s_idx[256];
    __shared__ float s_xseed[D];
    __shared__ float s_part[256];
    __shared__ float s_r[PROJ];

    // argmax (first occurrence of max, matching np.argmax)
    float bestv = -1e30f; int besti = 0;
    for (int i = t; i < N; i += 256) {
        float vv = cluster_mask[b * N + i];
        if (vv > bestv) { bestv = vv; besti = i; }  // strict > keeps lowest index
    }
    s_red[t] = bestv; s_idx[t] = besti;
    __syncthreads();
    for (int s = 128; s > 0; s >>= 1) {
        if (t < s) {
            float v2 = s_red[t + s]; int i2 = s_idx[t + s];
            if (v2 > s_red[t] || (v2 == s_red[t] && i2 < s_idx[t])) {
                s_red[t] = v2; s_idx[t] = i2;
            }
        }
        __syncthreads();
    }
    const int seed = s_idx[0];

    // stage x[b, seed, :]
    s_xseed[t] = x[(size_t)b * N * D + (size_t)seed * D + t];
    __syncthreads();

    // r[j] = sum_d x_seed[d] * Wq[d*64+j]   (PROJ=64)
    // split-K: 4 threads per output (quarter q covers d in [q*64, q*64+64))
    {
        const int j = t & 63;
        const int q = t >> 6;
        const float* wq = Wq + (size_t)(q * 64) * PROJ + j;
        const float* xs = s_xseed + q * 64;
        float acc = 0.f;
        #pragma unroll 8
        for (int d = 0; d < 64; ++d)
            acc += xs[d] * wq[d * PROJ];
        s_part[t] = acc;
    }
    __syncthreads();
    if (t < PROJ)
        s_r[t] = s_part[t] + s_part[t + 64] + s_part[t + 128] + s_part[t + 192];
    __syncthreads();

    // v[t] = (Wk[t,:] . r) / sqrt(PROJ)   (row-contiguous -> float4)
    {
        const float4* wk = (const float4*)(Wk + (size_t)t * PROJ);
        float acc = 0.f;
        #pragma unroll
        for (int j4 = 0; j4 < PROJ / 4; ++j4) {
            float4 w = wk[j4];
            float4 r4 = *(const float4*)&s_r[j4 * 4];
            acc += w.x * r4.x + w.y * r4.y + w.z * r4.z + w.w * r4.w;
        }
        v_ws[b * D + t] = acc * 0.125f;
    }
}

// -------------------- kernel 2: streaming adj pass -> deg, e2c, score -> p
// Each wave handles TWO rows (n0 = row0+wave, n1 = n0+4) interleaved: 32 nt-loads
// in flight per lane per loop body, one drain point per pair, LDS mask shared.
__global__ __launch_bounds__(256) void score_kernel(
    const float* __restrict__ x, const float* __restrict__ adj,
    const float* __restrict__ cluster_mask, const float* __restrict__ cand_mask,
    const float* __restrict__ v_ws, const float* __restrict__ theta_ws,
    float* __restrict__ p_ws)
{
    const int b = blockIdx.x / BLOCKS_PER_BATCH;
    const int chunk = blockIdx.x % BLOCKS_PER_BATCH;
    const int t = threadIdx.x;
    const int wave = t >> 6;
    const int lane = t & 63;

    __shared__ float s_mask[N];   // 16 KB
    __shared__ float s_v[D];

    for (int i = t * 4; i < N; i += 1024)
        *(float4*)&s_mask[i] = *(const float4*)&cluster_mask[b * N + i];
    if (t < D) s_v[t] = v_ws[b * D + t];
    __syncthreads();

    const float theta = theta_ws[b];
    const int row0 = chunk * ROWS_PER_BLOCK;

    const int n0 = row0 + wave;          // rows n0 and n0+4
    const int n1 = n0 + 4;
    const float* arow0 = adj + (size_t)b * N * N + (size_t)n0 * N;
    const float* arow1 = adj + (size_t)b * N * N + (size_t)n1 * N;

    float deg0 = 0.f, e2c0 = 0.f, deg1 = 0.f, e2c1 = 0.f;
    // adj is 268 MB streamed exactly once: nontemporal (L2-bypass) measured
    // faster than cached loads for this stream (428.4 vs 442.0 µs).
    #pragma unroll
    for (int k = 0; k < N / 256; ++k) {               // 16 iterations
        const int i = lane * 4 + k * 256;
        floatx4 a0 = __builtin_nontemporal_load((const floatx4*)&arow0[i]);
        floatx4 a1 = __builtin_nontemporal_load((const floatx4*)&arow1[i]);
        float4 m = *(const float4*)&s_mask[i];
        deg0 += a0.x + a0.y + a0.z + a0.w;
        e2c0 += a0.x * m.x + a0.y * m.y + a0.z * m.z + a0.w * m.w;
        deg1 += a1.x + a1.y + a1.z + a1.w;
        e2c1 += a1.x * m.x + a1.y * m.y + a1.z * m.z + a1.w * m.w;
    }
    // scores = x[b,n,:] . v   (256 floats = 64 lanes x float4)
    float sc0, sc1;
    {
        const float* xrow0 = x + (size_t)b * N * D + (size_t)n0 * D;
        const float* xrow1 = x + (size_t)b * N * D + (size_t)n1 * D;
        float4 xv0 = *(const float4*)&xrow0[lane * 4];
        float4 xv1 = *(const float4*)&xrow1[lane * 4];
        float4 vv  = *(const float4*)&s_v[lane * 4];
        sc0 = xv0.x * vv.x + xv0.y * vv.y + xv0.z * vv.z + xv0.w * vv.w;
        sc1 = xv1.x * vv.x + xv1.y * vv.y + xv1.z * vv.z + xv1.w * vv.w;
    }
    for (int off = 32; off > 0; off >>= 1) {
        deg0 += __shfl_down(deg0, off, 64);
        e2c0 += __shfl_down(e2c0, off, 64);
        sc0  += __shfl_down(sc0,  off, 64);
        deg1 += __shfl_down(deg1, off, 64);
        e2c1 += __shfl_down(e2c1, off, 64);
        sc1  += __shfl_down(sc1,  off, 64);
    }
    if (lane == 0) {
        float d0 = fmaxf(deg0, 1.0f);
        float cand0 = sc0 + ALPHA * (e2c0 / d0);
        float p0 = cand_mask[b * N + n0] / (1.f + expf(-(cand0 - theta)));  // TAU == 1
        p_ws[b * N + n0] = p0;
        float d1 = fmaxf(deg1, 1.0f);
        float cand1 = sc1 + ALPHA * (e2c1 / d1);
        float p1 = cand_mask[b * N + n1] / (1.f + expf(-(cand1 - theta)));
        p_ws[b * N + n1] = p1;
    }
}

// -------------------- kernel 3: top-K_CAP trim + outputs (one block per batch)
__global__ __launch_bounds__(256) void finalize_kernel(float* p_in, float* out)
{
    const int b = blockIdx.x;
    const int t = threadIdx.x;
    __shared__ float        sp[N];          // 16 KB
    __shared__ unsigned int hist[256];
    __shared__ float        s_red[256];
    __shared__ unsigned int s_cnt[256];
    __shared__ unsigned int s_scan[256];
    __shared__ unsigned int s_bcast[2];

    for (int i = t * 4; i < N; i += 1024)
        *(float4*)&sp[i] = *(const float4*)&p_in[b * N + i];
    __syncthreads();

    // count p > 0.5
    {
        unsigned int c = 0;
        for (int i = t; i < N; i += 256) c += (sp[i] > 0.5f) ? 1u : 0u;
        s_cnt[t] = c;
    }
    __syncthreads();
    for (int s = 128; s > 0; s >>= 1) { if (t < s) s_cnt[t] += s_cnt[t + s]; __syncthreads(); }
    const unsigned int over_cnt = s_cnt[0];
    __syncthreads();
    const bool need_trim = over_cnt > K_CAP;

    unsigned int prefix = 0u;       // bit pattern of the K_CAP-th largest value
    unsigned int k_rem = K_CAP;     // becomes #ties-to-keep after last pass
    if (need_trim) {
        for (int pass = 0; pass < 4; ++pass) {
            const int shift = 24 - pass * 8;
            const unsigned int himask = (pass == 0) ? 0u : (0xFFFFFFFFu << (shift + 8));
            hist[t] = 0u;
            __syncthreads();
            for (int i = t; i < N; i += 256) {
                unsigned int u = __float_as_uint(sp[i]);
                if ((u & himask) == prefix)
                    atomicAdd(&hist[(u >> shift) & 255u], 1u);
            }
            __syncthreads();
            // suffix inclusive scan of hist -> s_scan[t] = sum_{j>=t} hist[j]
            s_scan[t] = hist[t];
            __syncthreads();
            for (int off = 1; off < 256; off <<= 1) {
                unsigned int add = (t + off < 256) ? s_scan[t + off] : 0u;
                __syncthreads();
                s_scan[t] += add;
                __syncthreads();
            }
            const unsigned int Ginc = s_scan[t];
            const unsigned int G = Ginc - hist[t];     // count strictly above bin t
            if (G < k_rem && k_rem <= Ginc) {
                s_bcast[0] = prefix | ((unsigned int)t << shift);
                s_bcast[1] = k_rem - G;
            }
            __syncthreads();
            prefix = s_bcast[0];
            k_rem  = s_bcast[1];
            __syncthreads();
        }
    }
    const float vk = __uint_as_float(prefix);
    const unsigned int t_keep = k_rem;   // first t_keep ties (by index) are kept

    // exclusive prefix of tie counts over contiguous 16-element chunks
    unsigned int tie_excl = 0;
    if (need_trim) {
        unsigned int local_tie = 0;
        const int base = t * 16;
        for (int j = 0; j < 16; ++j)
            local_tie += (__float_as_uint(sp[base + j]) == prefix) ? 1u : 0u;
        s_cnt[t] = local_tie;
        __syncthreads();
        s_scan[t] = local_tie;
        __syncthreads();
        for (int off = 1; off < 256; off <<= 1) {
            unsigned int add = (t >= off) ? s_scan[t - off] : 0u;
            __syncthreads();
            s_scan[t] += add;
            __syncthreads();
        }
        tie_excl = s_scan[t] - s_cnt[t];
        __syncthreads();
    }

    // final: trim, write hard + p, accumulate sum
    float psum = 0.f;
    {
        const int base = t * 16;
        unsigned int tie_rank = tie_excl;
        for (int j = 0; j < 16; ++j) {
            const int i = base + j;
            float p = sp[i];
            if (need_trim) {
                const unsigned int u = __float_as_uint(p);
                bool keep;
                if (u == prefix) { keep = (tie_rank < t_keep); tie_rank++; }
                else             { keep = (p > vk); }
                if (!keep) p = 0.f;
            }
            out[b * N + i]         = (p > 0.5f) ? 1.0f : 0.0f;  // hard gate
            out[B * N + b * N + i] = p;                          // trimmed p
            psum += p;
        }
    }
    s_red[t] = psum;
    __syncthreads();
    for (int s = 128; s > 0; s >>= 1) { if (t < s) s_red[t] += s_red[t + s]; __syncthreads(); }
    if (t == 0) {
        out[2 * B * N + B + b]     = s_red[0];                   // expected_size
        out[2 * B * N + 2 * B + b] = s_red[0] * (1.0f / N);      // mean_p
    }
}

extern "C" void kernel_launch(void* const* d_in, const int* in_sizes, int n_in,
                              void* d_out, int out_size, void* d_ws, size_t ws_size,
                              hipStream_t stream) {
    const float* x            = (const float*)d_in[0];
    const float* adj          = (const float*)d_in[1];
    const float* seed_ctx     = (const float*)d_in[2];
    const float* local_stats  = (const float*)d_in[3];
    const float* cluster_mask = (const float*)d_in[4];
    const float* cand_mask    = (const float*)d_in[5];
    const float* Wq           = (const float*)d_in[6];
    const float* Wk           = (const float*)d_in[7];
    const float* th_w1        = (const float*)d_in[8];
    const float* th_b1        = (const float*)d_in[9];
    const float* th_w2        = (const float*)d_in[10];
    const float* th_b2        = (const float*)d_in[11];
    float* out = (float*)d_out;

    // Scratch aliased onto d_out regions that are fully overwritten later:
    //   v_ws   -> out[0 .. B*D)          (hard region, rewritten by finalize)
    //   theta  -> out[2BN .. 2BN+B)      (the actual theta output slot)
    //   p_ws   -> out[BN .. 2BN)         (p region, read-then-rewritten by finalize)
    float* v_ws     = out;
    float* p_ws     = out + B * N;
    float* theta_ws = out + 2 * B * N;

    hipLaunchKernelGGL(prep_kernel, dim3(2 * B), dim3(256), 0, stream,
                       x, cluster_mask, seed_ctx, local_stats, Wq, Wk,
                       th_w1, th_b1, th_w2, th_b2, v_ws, theta_ws);
    hipLaunchKernelGGL(score_kernel, dim3(B * BLOCKS_PER_BATCH), dim3(256), 0, stream,
                       x, adj, cluster_mask, cand_mask, v_ws, theta_ws, p_ws);
    hipLaunchKernelGGL(finalize_kernel, dim3(B), dim3(256), 0, stream,
                       p_ws, out);
}